// Round 9
// baseline (89.752 us; speedup 1.0000x reference)
//
#include <hip/hip_runtime.h>

typedef unsigned int u32;
typedef _Float16 f16;
typedef f16 f16x2 __attribute__((ext_vector_type(2)));
typedef f16 f16x4 __attribute__((ext_vector_type(4)));
typedef f16 f16x8 __attribute__((ext_vector_type(8)));
typedef float f32x4 __attribute__((ext_vector_type(4)));

#define LSEQ 900
#define BATCH 4
#define NWIN (BATCH*LSEQ)
#define NBLK NWIN         // encoder: 1 window/block
#define QT 2
#define NABLK (NWIN/QT)   // 1800

__device__ __forceinline__ float eluf(float x){ return x > 0.f ? x : __expf(x) - 1.f; }
#define BC2(u) __builtin_bit_cast(f16x2, (u))
#define ZERO8 __builtin_bit_cast(f16x8, (uint4{0,0,0,0}))

__device__ __forceinline__ f16x8 hmax8(f16x8 a, f16x8 b){
#if defined(__has_builtin) && __has_builtin(__builtin_elementwise_max)
  return __builtin_elementwise_max(a, b);
#else
  f16x8 r;
  #pragma unroll
  for (int i=0;i<8;++i) r[i] = a[i] > b[i] ? a[i] : b[i];
  return r;
#endif
}
__device__ __forceinline__ f16x4 hmax4(f16x4 a, f16x4 b){
#if defined(__has_builtin) && __has_builtin(__builtin_elementwise_max)
  return __builtin_elementwise_max(a, b);
#else
  f16x4 r;
  #pragma unroll
  for (int i=0;i<4;++i) r[i] = a[i] > b[i] ? a[i] : b[i];
  return r;
#endif
}

// ---- LDS map (u32 words), WPB=1 ----
#define P0U 0
#define P1U 2112
#define FEATU 3872
#define F32U 4080
#define SMTOT 4288
#define T1F 0
#define H2F 4224
#define T2F 0
#define H3F 4224
#define T3F 0
#define FEATF 7744

// ---- ws f16 offsets ----
#define WB2A 0
#define WB2B 512
#define WB3  768
#define WB4  2304
#define WFC1 5376
#define WEND 58624
#define WC1  58624                 // C1: 4*900*80*4 f16 = 1152000
#define WTE  (WC1 + 1152000)       // TE: 1152000
#define WF32 ((WTE + 1152000)/2)   // f32 word offset: 1181312

#define PREP_BLOCKS ((WEND+255)/256)        // 229
#define CONV_BLOCKS ((144000+255)/256)      // 563  (2 cols per thread)

// ============ fused prep: weight packing + full-seq conv1 (2 cols/thread) ============
__global__ __launch_bounds__(256) void prep_all(
    const float* __restrict__ z,
    const float* __restrict__ cw1, const float* __restrict__ cb1,
    const float* __restrict__ cw2, const float* __restrict__ cw3,
    const float* __restrict__ cw4, const float* __restrict__ fc1w,
    f16* __restrict__ wsF, f16* __restrict__ C1, f16* __restrict__ TE)
{
  const int blk = blockIdx.x;
  if (blk < PREP_BLOCKS) {
    const int g = blk*256 + threadIdx.x;
    if (g >= WEND) return;
    float val;
    if (g < 512) {
      const int l = g>>3, j = g&7;
      const int oc = l&15, c = l>>4;
      const int dr = c>>1, dc = 2*(c&1) + (j>>2), ic = j&3;
      val = (oc<8 && dc<3) ? cw2[oc*36 + ic*9 + dr*3 + dc] : 0.f;
    } else if (g < 768) {
      const int u = g-512, l = u>>2, j = u&3;
      const int oc = l&15, dc = l>>4, ic = j;
      val = (oc<8 && dc<3) ? cw2[oc*36 + ic*9 + 6 + dc] : 0.f;
    } else if (g < 2304) {
      const int u = g-768, dr = u>>9, r = u&511, l = r>>3, j = r&7;
      const int oc = l&15, dc = l>>4, ic = j;
      val = (dc<3) ? cw3[oc*72 + ic*9 + dr*3 + dc] : 0.f;
    } else if (g < 5376) {
      const int u = g-2304, v = u>>9, dr = v>>1, h = v&1;
      const int r = u&511, l = r>>3, j = r&7;
      const int oc = l&15, chunk = l>>4;
      const int dcl = chunk>>1, ic = (chunk&1)*8 + j, dc = h*2 + dcl;
      val = (dc<3) ? cw4[oc*144 + ic*9 + dr*3 + dc] : 0.f;
    } else {
      const int u = g - WFC1;
      const int j = u&7, l = (u>>3)&63, st = (u>>9)%13, nt = u/(13*512);
      const int k = st*32 + (l>>4)*8 + j, n = nt*16 + (l&15);
      val = (k<400) ? fc1w[n*400 + k] : 0.f;
    }
    wsF[g] = (f16)val;
  } else {
    const int g = (blk - PREP_BLOCKS)*256 + threadIdx.x;   // 0..143999: (b,f,colpair)
    if (g >= 144000) return;
    const int cp = g % 40, fb2 = g / 40, f = fb2 % 900, b = fb2 / 900;
    const int c0 = 2*cp;
    const float* zb = z + b*72000;
    float p[3][4];
    #pragma unroll
    for (int dr = 0; dr < 3; ++dr) {
      const int r = f + dr - 1;
      const bool rok = (r >= 0) && (r < 900);
      #pragma unroll
      for (int dc = 0; dc < 4; ++dc) {
        const int cc = c0 + dc - 1;
        p[dr][dc] = (rok && cc >= 0 && cc < 80) ? zb[r*80+cc] : 0.f;
      }
    }
    f16x8 cf, te;
    #pragma unroll
    for (int col = 0; col < 2; ++col) {
      #pragma unroll
      for (int oc = 0; oc < 4; ++oc) {
        float s12 = cb1[oc], s0 = 0.f;
        #pragma unroll
        for (int dc = 0; dc < 3; ++dc) {
          s0  += cw1[oc*9 + dc]     * p[0][col+dc];
          s12 += cw1[oc*9 + 3 + dc] * p[1][col+dc];
          s12 += cw1[oc*9 + 6 + dc] * p[2][col+dc];
        }
        te[col*4+oc] = (f16)s12;
        cf[col*4+oc] = (f16)(s12 + s0);
      }
    }
    *(f16x8*)(C1 + g*8) = cf;
    *(f16x8*)(TE + g*8) = te;
  }
}

// ============ encoder WPB=1: stage1 gather; stages 2-4 + fc1 MFMA; small LDS ============
__global__ __launch_bounds__(256,8) void encoder4(
    const f16* __restrict__ C1, const f16* __restrict__ TE,
    const float* __restrict__ toh,
    const float* __restrict__ cb2, const float* __restrict__ cb3, const float* __restrict__ cb4,
    const f16* __restrict__ wsF,
    const float* __restrict__ fc1b, const float* __restrict__ fc2w, const float* __restrict__ fc2b,
    const float* __restrict__ embw, const float* __restrict__ embb,
    const float* __restrict__ wq, const float* __restrict__ bq,
    const float* __restrict__ wk, const float* __restrict__ bk,
    const float* __restrict__ wv, const float* __restrict__ bv,
    float* __restrict__ zt_g, float* __restrict__ q_g,
    float* __restrict__ k_g, float* __restrict__ v_g)
{
  __shared__ __align__(16) u32 sm[SMTOT];
  f16* smh = (f16*)sm;
  const int tid = threadIdx.x, blk = blockIdx.x;
  const int lane = tid & 63, wid = tid >> 6;
  const int b = blk/LSEQ, i0 = blk%LSEQ;

  // zero P0 (T1 incl. borders) + FEAT
  {
    const uint4 z4 = {0,0,0,0};
    uint4* p0 = (uint4*)(sm + P0U);
    for (int t = tid; t < 528; t += 256) p0[t] = z4;
    uint4* pf = (uint4*)(sm + FEATU);
    if (tid < 52) pf[tid] = z4;
  }
  __syncthreads();

  // ---- stage1: gather C1/TE rows + pool2x2 + elu -> T1 NHWC [24][44][4] ----
  {
    const int e45 = min(i0 + 23, LSEQ) - 45;
    const int sv  = max(i0 - 22, 0);
    const f16* C1b = C1 + b*288000;
    const f16* TEb = TE + b*288000;
    for (int s = tid; s < 880; s += 256) {
      const int pr = s/40, pc = s%40;
      const int fa = e45 + 2*pr, fb = fa + 1;
      const f16* srcA = (fa == sv) ? TEb : C1b;
      const f16* srcB = (fb == sv) ? TEb : C1b;
      f16x8 va = *(const f16x8*)(srcA + (max(fa,0)*80 + 2*pc)*4);
      f16x8 vb = *(const f16x8*)(srcB + (max(fb,0)*80 + 2*pc)*4);
      if (fa < sv) va = ZERO8;
      if (fb < sv) vb = ZERO8;
      const f16x8 m8 = hmax8(va, vb);
      const f16x4 lo = __builtin_shufflevector(m8, m8, 0,1,2,3);
      const f16x4 hi = __builtin_shufflevector(m8, m8, 4,5,6,7);
      const f16x4 m4 = hmax4(lo, hi);
      f16x4 ov;
      #pragma unroll
      for (int oc = 0; oc < 4; ++oc) ov[oc] = (f16)eluf((float)m4[oc]);
      *(f16x4*)(smh + T1F + ((pr+1)*44 + pc+1)*4) = ov;
    }
  }
  __syncthreads();

  // ---- stage2 MFMA: T1 -> conv(4->8); hmax -> H2 [22][20][8]; incremental addressing ----
  {
    const f16x8 B2a = *(const f16x8*)(wsF + WB2A + lane*8);
    const f16x4 B2b = *(const f16x4*)(wsF + WB2B + lane*4);
    const int oc = lane&15, chunk = lane>>4;
    const float bias2 = (oc<8) ? cb2[oc] : 0.f;
    int r2 = (wid*16 + oc)/40, c2 = (wid*16 + oc)%40;
    int rE = (wid*16 + chunk*4)/40, cE = (wid*16 + chunk*4)%40;
    for (int t = wid; t < 55; t += 4) {
      const f16* base = smh + T1F;
      const f16* pA = base + ((r2 + (chunk>>1))*44 + c2 + 2*(chunk&1))*4;
      const f16x4 lo = *(const f16x4*)(pA);
      const f16x4 hi = *(const f16x4*)(pA + 4);
      const f16x8 a8 = __builtin_shufflevector(lo, hi, 0,1,2,3,4,5,6,7);
      f32x4 acc = {bias2, bias2, bias2, bias2};
      acc = __builtin_amdgcn_mfma_f32_16x16x32_f16(a8, B2a, acc, 0, 0, 0);
      const f16x4 a4 = *(const f16x4*)(base + ((r2+2)*44 + c2 + chunk)*4);
      acc = __builtin_amdgcn_mfma_f32_16x16x16f16(a4, B2b, acc, 0, 0, 0);
      if (oc < 8) {
        f16* h2o = smh + H2F;
        h2o[(rE*20 + (cE>>1))*8 + oc] = (f16)fmaxf(acc[0], acc[1]);
        const int cE2 = cE + 2;
        const int rE2 = rE + (cE2 >= 40 ? 1 : 0);
        const int cE3 = cE2 >= 40 ? cE2 - 40 : cE2;
        h2o[(rE2*20 + (cE3>>1))*8 + oc] = (f16)fmaxf(acc[2], acc[3]);
      }
      { const int cn = c2 + 24; const int cy = cn >= 40;
        r2 += 1 + cy; c2 = cy ? cn - 40 : cn; }
      { const int cn = cE + 24; const int cy = cn >= 40;
        rE += 1 + cy; cE = cy ? cn - 40 : cn; }
    }
  }
  __syncthreads();

  // ---- vertical max + elu: H2 -> T2 NHWC [13][24][8]; zero T2 border ----
  {
    for (int s = tid; s < 312; s += 256) {
      const int r = s/24, c = s%24;
      if (!(r>=1 && r<=11 && c>=1 && c<=20)) {
        const uint4 z4 = {0,0,0,0};
        *(uint4*)(smh + T2F + (r*24+c)*8) = z4;
      }
    }
    for (int s = tid; s < 880; s += 256) {
      const int pr = s/80, rem = s%80, cp = rem/4, op = rem%4;
      const u32* h2 = (const u32*)(smh + H2F);
      const u32 a  = h2[((2*pr  )*20 + cp)*4 + op];
      const u32 b2 = h2[((2*pr+1)*20 + cp)*4 + op];
      const f16x2 av = BC2(a), bv = BC2(b2);
      f16x2 o;
      o.x = (f16)eluf(fmaxf((float)av.x, (float)bv.x));
      o.y = (f16)eluf(fmaxf((float)av.y, (float)bv.y));
      ((u32*)(smh + T2F))[((pr+1)*24 + cp+1)*4 + op] = __builtin_bit_cast(u32, o);
    }
  }
  __syncthreads();

  // ---- stage3 MFMA: T2 -> conv(8->16); hmax -> H3 [10][10][16] ----
  {
    f16x8 B3r[3];
    #pragma unroll
    for (int dr = 0; dr < 3; ++dr) B3r[dr] = *(const f16x8*)(wsF + WB3 + dr*512 + lane*8);
    const int oc = lane&15, chunk = lane>>4;
    const float bias3 = cb3[oc];
    for (int t = wid; t < 14; t += 4) {
      const int mA = t*16 + oc;
      const int r3 = mA/20, c3 = mA%20;
      const f16* base = smh + T2F;
      f32x4 acc = {bias3, bias3, bias3, bias3};
      #pragma unroll
      for (int dr = 0; dr < 3; ++dr) {
        const f16x8 a8 = *(const f16x8*)(base + ((r3+dr)*24 + c3 + chunk)*8);
        acc = __builtin_amdgcn_mfma_f32_16x16x32_f16(a8, B3r[dr], acc, 0, 0, 0);
      }
      #pragma unroll
      for (int p = 0; p < 2; ++p) {
        const int mE = t*16 + chunk*4 + 2*p;
        if (mE < 220) {
          const int rE = mE/20, cE = mE%20;
          if (rE < 10)
            smh[H3F + (rE*10 + (cE>>1))*16 + oc] = (f16)fmaxf(acc[2*p], acc[2*p+1]);
        }
      }
    }
  }
  __syncthreads();

  // ---- vertical max + elu: H3 -> T3 NHWC [7][14][16]; zero T3 border ----
  {
    for (int s = tid; s < 98; s += 256) {
      const int r = s/14, c = s%14;
      if (!(r>=1 && r<=5 && c>=1 && c<=10)) {
        const uint4 z4 = {0,0,0,0};
        *(uint4*)(smh + T3F + (r*14+c)*16)     = z4;
        *(uint4*)(smh + T3F + (r*14+c)*16 + 8) = z4;
      }
    }
    for (int s = tid; s < 400; s += 256) {
      const int pr = s/80, rem = s%80, cp = rem/8, op = rem%8;
      const u32* h3 = (const u32*)(smh + H3F);
      const u32 a  = h3[((2*pr  )*10 + cp)*8 + op];
      const u32 b2 = h3[((2*pr+1)*10 + cp)*8 + op];
      const f16x2 av = BC2(a), bv = BC2(b2);
      f16x2 o;
      o.x = (f16)eluf(fmaxf((float)av.x, (float)bv.x));
      o.y = (f16)eluf(fmaxf((float)av.y, (float)bv.y));
      ((u32*)(smh + T3F))[((pr+1)*14 + cp+1)*8 + op] = __builtin_bit_cast(u32, o);
    }
  }
  __syncthreads();

  // ---- stage4 MFMA: T3 -> conv(16->16) + pool1x2 + elu -> feat NCHW f16[400] in LDS ----
  {
    f16x8 B4r[6];
    #pragma unroll
    for (int v = 0; v < 6; ++v) B4r[v] = *(const f16x8*)(wsF + WB4 + v*512 + lane*8);
    const int oc = lane&15, chunk = lane>>4;
    const int dcl = chunk>>1, hsel = chunk&1;
    const float bias4 = cb4[oc];
    for (int t = wid; t < 4; t += 4) {
      const int mA = t*16 + oc;
      const int mmA = mA < 50 ? mA : mA - 50;
      const int r4 = mmA/10, c4 = mmA%10;
      const f16* base = smh + T3F;
      f32x4 acc = {bias4, bias4, bias4, bias4};
      #pragma unroll
      for (int v = 0; v < 6; ++v) {
        const int dr = v>>1, h = v&1;
        const f16x8 a8 = *(const f16x8*)(base + ((r4+dr)*14 + c4 + h*2 + dcl)*16 + hsel*8);
        acc = __builtin_amdgcn_mfma_f32_16x16x32_f16(a8, B4r[v], acc, 0, 0, 0);
      }
      #pragma unroll
      for (int p = 0; p < 2; ++p) {
        const int mE = t*16 + chunk*4 + 2*p;
        if (mE < 50) {
          const int rE = mE/10, cE = mE%10;
          smh[FEATF + oc*25 + rE*5 + (cE>>1)] = (f16)eluf(fmaxf(acc[2*p], acc[2*p+1]));
        }
      }
    }
  }
  __syncthreads();

  // ---- fc1 MFMA: feat[416] x fc1B -> h1 f32[128], elu ----
  {
    float* h1 = (float*)(sm + F32U);
    #pragma unroll
    for (int q2 = 0; q2 < 2; ++q2) {
      const int nt = wid + q2*4;
      f32x4 acc = {0.f, 0.f, 0.f, 0.f};
      for (int st = 0; st < 13; ++st) {
        const f16x8 a8 = *(const f16x8*)(smh + FEATF + st*32 + (lane>>4)*8);
        const f16x8 b8 = *(const f16x8*)(wsF + WFC1 + ((nt*13 + st)*64 + lane)*8);
        acc = __builtin_amdgcn_mfma_f32_16x16x32_f16(a8, b8, acc, 0, 0, 0);
      }
      if (lane < 16) {
        const int n = nt*16 + lane;
        h1[n] = eluf(acc[0] + fc1b[n]);
      }
    }
  }
  __syncthreads();

  // ---- fc2 -> emb -> qkv ----
  float* fregion = (float*)(sm + F32U);
  float* h1f = fregion;
  float* zpf = fregion + 128;
  float* ztf = fregion + 168;
  if (tid < 40) {
    const int n = tid;
    const float4* hv = (const float4*)h1f;
    const float4* wr = (const float4*)(fc2w + n*128);
    float acc = fc2b[n];
    #pragma unroll 8
    for (int c = 0; c < 32; ++c) {
      const float4 a = wr[c], x = hv[c];
      acc += a.x*x.x + a.y*x.y + a.z*x.z + a.w*x.w;
    }
    zpf[n] = acc;
  }
  __syncthreads();
  if (tid < 40) {
    const int n = tid;
    const float* wr = embw + n*45;
    float acc = embb[n];
    #pragma unroll 8
    for (int j = 0; j < 40; ++j) acc += wr[j]*zpf[j];
    #pragma unroll
    for (int j = 0; j < 5; ++j)  acc += wr[40+j]*toh[b*5 + j];
    const float v2 = eluf(acc);
    ztf[n] = v2;
    zt_g[(b*LSEQ + i0)*40 + n] = v2;
  }
  __syncthreads();
  if (tid < 120) {
    const int which = tid/40, n = tid%40;
    const float* wm = which==0 ? wq : (which==1 ? wk : wv);
    const float* bb = which==0 ? bq : (which==1 ? bk : bv);
    const float4* wr = (const float4*)(wm + n*40);
    const float4* zv = (const float4*)ztf;
    float acc = bb[n];
    #pragma unroll
    for (int c = 0; c < 10; ++c) {
      const float4 a = wr[c], x = zv[c];
      acc += a.x*x.x + a.y*x.y + a.z*x.z + a.w*x.w;
    }
    float* dst = which==0 ? q_g : (which==1 ? k_g : v_g);
    dst[(b*LSEQ + i0)*40 + n] = acc;
  }
}

// ============ attention: QT=2 query rows per block (1800 blocks); no max-shift ============
__global__ __launch_bounds__(256) void attn5(
    const float* __restrict__ q_g, const float* __restrict__ k_g,
    const float* __restrict__ v_g, const float* __restrict__ zt_g,
    const int* __restrict__ dur,
    const float* __restrict__ flw1, const float* __restrict__ flb1,
    const float* __restrict__ flw2, const float* __restrict__ flb2,
    const float* __restrict__ stw1, const float* __restrict__ stb1,
    const float* __restrict__ stw2, const float* __restrict__ stb2,
    const float* __restrict__ edw1, const float* __restrict__ edb1,
    const float* __restrict__ edw2, const float* __restrict__ edb2,
    float* __restrict__ out)
{
  __shared__ __align__(16) float sq[QT][40];
  __shared__ __align__(16) float szt[QT][40];
  __shared__ __align__(16) float esm[QT][904];
  __shared__ float red[4][QT];
  __shared__ float spart[6][QT][41];
  __shared__ __align__(16) float xr[QT][40];
  __shared__ float hb[QT][30];

  const int tid = threadIdx.x;
  const int blk = blockIdx.x;
  const int b = blk / (LSEQ/QT);
  const int q0 = (blk % (LSEQ/QT)) * QT;
  const int durb = dur[b];

  for (int t = tid; t < QT*40*2; t += 256) {
    const int which = t / (QT*40), r = t % (QT*40);
    const int q = r/40, d = r%40;
    const float v = (which ? zt_g : q_g)[(b*LSEQ + q0 + q)*40 + d];
    if (which) szt[q][d] = v; else sq[q][d] = v;
  }
  __syncthreads();

  const float scale = 0.15811388300841897f;   // 1/sqrt(40)
  float ls[QT] = {0.f, 0.f};
  for (int m = tid; m < LSEQ; m += 256) {
    if (m < durb) {
      float4 kv[10];
      const float4* kr4 = (const float4*)(k_g + (b*LSEQ+m)*40);
      #pragma unroll
      for (int j = 0; j < 10; ++j) kv[j] = kr4[j];
      #pragma unroll
      for (int q = 0; q < QT; ++q) {
        float e;
        if (q0 + q < durb) {
          const float4* qv = (const float4*)(&sq[q][0]);
          float acc = 0.f;
          #pragma unroll
          for (int j = 0; j < 10; ++j) {
            const float4 a = kv[j], x = qv[j];
            acc += a.x*x.x + a.y*x.y + a.z*x.z + a.w*x.w;
          }
          e = __expf(acc*scale);
        } else e = 1.f;            // exp(-1e-12) == 1.0f
        esm[q][m] = e;
        ls[q] += e;
      }
    } else {
      #pragma unroll
      for (int q = 0; q < QT; ++q) { esm[q][m] = 1.f; ls[q] += 1.f; }
    }
  }
  #pragma unroll
  for (int q = 0; q < QT; ++q) {
    float s = ls[q];
    #pragma unroll
    for (int off = 32; off > 0; off >>= 1) s += __shfl_xor(s, off);
    if ((tid & 63) == 0) red[tid >> 6][q] = s;
  }
  __syncthreads();

  // PV: 240 threads = (chunk c of 150 rows, dim d); each accumulates both rows
  if (tid < 240) {
    const int c = tid/40, d = tid%40;
    const float* vb = v_g + (b*LSEQ + c*150)*40 + d;
    const int m0 = c*150;
    float a0=0.f, a1=0.f;
    for (int mm = 0; mm < 150; ++mm) {
      const float vv = vb[mm*40];
      a0 += esm[0][m0+mm]*vv; a1 += esm[1][m0+mm]*vv;
    }
    spart[c][0][d] = a0; spart[c][1][d] = a1;
  }
  __syncthreads();

  if (tid < QT*40) {
    const int q = tid/40, d = tid%40;
    const float den = red[0][q] + red[1][q] + red[2][q] + red[3][q];
    float xv = 0.f;
    #pragma unroll
    for (int c = 0; c < 6; ++c) xv += spart[c][q][d];
    xr[q][d] = xv/den + szt[q][d];
  }
  __syncthreads();

  if (tid < QT*30) {
    const int q = tid/30, rr = tid%30, hd = rr/10, j = rr%10;
    const float* w1 = hd==0?flw1:(hd==1?stw1:edw1);
    const float* b1 = hd==0?flb1:(hd==1?stb1:edb1);
    float a = b1[j];
    #pragma unroll 8
    for (int d = 0; d < 40; ++d) a += w1[j*40+d]*xr[q][d];
    hb[q][hd*10+j] = eluf(a);
  }
  __syncthreads();
  if (tid < QT*3) {
    const int q = tid/3, hd = tid%3;
    const float* w2 = hd==0?flw2:(hd==1?stw2:edw2);
    const float* b2 = hd==0?flb2:(hd==1?stb2:edb2);
    float a = b2[0];
    #pragma unroll
    for (int j = 0; j < 10; ++j) a += w2[j]*hb[q][hd*10+j];
    out[hd*NWIN + b*LSEQ + q0 + q] = a;
  }
}

extern "C" void kernel_launch(void* const* d_in, const int* in_sizes, int n_in,
                              void* d_out, int out_size, void* d_ws, size_t ws_size,
                              hipStream_t stream) {
  const float* z    = (const float*)d_in[0];
  const float* toh  = (const float*)d_in[1];
  const int*   dur  = (const int*)d_in[2];
  const float* cw1  = (const float*)d_in[3];
  const float* cb1  = (const float*)d_in[4];
  const float* cw2  = (const float*)d_in[5];
  const float* cb2  = (const float*)d_in[6];
  const float* cw3  = (const float*)d_in[7];
  const float* cb3  = (const float*)d_in[8];
  const float* cw4  = (const float*)d_in[9];
  const float* cb4  = (const float*)d_in[10];
  const float* fc1w = (const float*)d_in[11];
  const float* fc1b = (const float*)d_in[12];
  const float* fc2w = (const float*)d_in[13];
  const float* fc2b = (const float*)d_in[14];
  const float* embw = (const float*)d_in[15];
  const float* embb = (const float*)d_in[16];
  const float* wq   = (const float*)d_in[17];
  const float* bq   = (const float*)d_in[18];
  const float* wk   = (const float*)d_in[19];
  const float* bk   = (const float*)d_in[20];
  const float* wv   = (const float*)d_in[21];
  const float* bv   = (const float*)d_in[22];
  const float* flw1 = (const float*)d_in[23];
  const float* flb1 = (const float*)d_in[24];
  const float* flw2 = (const float*)d_in[25];
  const float* flb2 = (const float*)d_in[26];
  const float* stw1 = (const float*)d_in[27];
  const float* stb1 = (const float*)d_in[28];
  const float* stw2 = (const float*)d_in[29];
  const float* stb2 = (const float*)d_in[30];
  const float* edw1 = (const float*)d_in[31];
  const float* edb1 = (const float*)d_in[32];
  const float* edw2 = (const float*)d_in[33];
  const float* edb2 = (const float*)d_in[34];

  f16*   wsF = (f16*)d_ws;
  f16*   C1  = wsF + WC1;
  f16*   TE  = wsF + WTE;
  float* wsf = (float*)d_ws;
  float* zt = wsf + WF32;
  float* q  = wsf + WF32 + 144000;
  float* k  = wsf + WF32 + 288000;
  float* v  = wsf + WF32 + 432000;

  prep_all<<<PREP_BLOCKS + CONV_BLOCKS, 256, 0, stream>>>(z, cw1, cb1, cw2, cw3, cw4, fc1w,
                                                          wsF, C1, TE);
  encoder4<<<NBLK, 256, 0, stream>>>(C1, TE, toh, cb2, cb3, cb4, wsF,
                                     fc1b, fc2w, fc2b, embw, embb,
                                     wq, bq, wk, bk, wv, bv, zt, q, k, v);
  attn5<<<NABLK, 256, 0, stream>>>(q, k, v, zt, dur,
                                   flw1, flb1, flw2, flb2,
                                   stw1, stb1, stw2, stb2,
                                   edw1, edb1, edw2, edb2,
                                   (float*)d_out);
}